// Round 8
// baseline (133.303 us; speedup 1.0000x reference)
//
#include <hip/hip_runtime.h>

typedef unsigned int uint;
typedef unsigned short ushort;
typedef __attribute__((ext_vector_type(8))) short bf16x8;
typedef __attribute__((ext_vector_type(16))) float f32x16;

#define LOG2E 1.44269504088896f
#define NB 16
#define NPIX 4096   // 64*64 pixels per image
#define MKEY 1024   // pooled keys per image

// MEASUREMENT ROUND: kernel bodies identical to R7. attn_kernel is launched
// TWICE (idempotent) so that dur_us(R8) - dur_us(R7) = attn's true marginal
// cost, which the fill-saturated top-5 profile cannot show.

// ---- helpers -------------------------------------------------------------
__device__ inline uint cvtpk(float lo, float hi) {   // pack 2 f32 -> bf16x2 (RNE)
    uint r;
    asm("v_cvt_pk_bf16_f32 %0, %1, %2" : "=v"(r) : "v"(lo), "v"(hi));
    return r;
}
union U4B8 { uint u[4]; bf16x8 b; };
__device__ inline f32x16 zero16() {
    f32x16 z;
#pragma unroll
    for (int i = 0; i < 16; ++i) z[i] = 0.0f;
    return z;
}

// ws layout: thetaT bf16 [16][4096][8]  (524288 ushort)
//            per-b kv    [16] x { phiT bf16 [1024][8] (8192 us) |
//                                 g_frag bf16 [64 T][64 lane][8 j] (32768 us) }

__global__ __launch_bounds__(256, 2) void proj_kernel(
    const float* __restrict__ x,   const float* __restrict__ Wth,
    const float* __restrict__ Wph, const float* __restrict__ Wg,
    ushort* __restrict__ thetaT,   ushort* __restrict__ kv)
{
    __shared__ float wTs[64][66];       // [oc][c]
    __shared__ float pool_s[40][128];   // phi(0-7)/g(8-39) per-pixel values

    const int t  = threadIdx.x;
    const int w  = t >> 6, l = t & 63, ql = l & 31, h = l >> 5;
    const int b  = blockIdx.x >> 5, rp = blockIdx.x & 31;
    const int pxb = w*32 + ql;          // 0..127 within 2 image rows
    const int n   = rp*128 + pxb;       // global pixel

    for (int i = t; i < 4096; i += 256) {
        const int o = i >> 6, c = i & 63;
        float v;
        if (o < 8)       v = Wth[i] * LOG2E;
        else if (o < 16) v = Wph[i - 512];
        else if (o < 48) v = Wg[i - 1024];
        else             v = 0.0f;
        wTs[o][c] = v;
    }

    const float* xb = x + (size_t)b*64*NPIX + n;
    float xv[32];
#pragma unroll
    for (int k = 0; k < 32; ++k) {
        const int s = k >> 3, j = k & 7;
        xv[k] = xb[(size_t)(s*16 + h*8 + j) * NPIX];
    }
    __syncthreads();

    bf16x8 wA[2][4];
#pragma unroll
    for (int T = 0; T < 2; ++T)
#pragma unroll
        for (int s = 0; s < 4; ++s) {
            const float* p = &wTs[T*32 + ql][s*16 + h*8];
            U4B8 cv;
            cv.u[0] = cvtpk(p[0],p[1]); cv.u[1] = cvtpk(p[2],p[3]);
            cv.u[2] = cvtpk(p[4],p[5]); cv.u[3] = cvtpk(p[6],p[7]);
            wA[T][s] = cv.b;
        }

    f32x16 c0 = zero16(), c1 = zero16();
#pragma unroll
    for (int s = 0; s < 4; ++s) {
        U4B8 cv;
        cv.u[0] = cvtpk(xv[s*8+0],xv[s*8+1]); cv.u[1] = cvtpk(xv[s*8+2],xv[s*8+3]);
        cv.u[2] = cvtpk(xv[s*8+4],xv[s*8+5]); cv.u[3] = cvtpk(xv[s*8+6],xv[s*8+7]);
        c0 = __builtin_amdgcn_mfma_f32_32x32x16_bf16(wA[0][s], cv.b, c0, 0,0,0);
        c1 = __builtin_amdgcn_mfma_f32_32x32x16_bf16(wA[1][s], cv.b, c1, 0,0,0);
    }

    {
        uint2 tv;
        tv.x = cvtpk(c0[0], c0[1]);
        tv.y = cvtpk(c0[2], c0[3]);
        *(uint2*)(thetaT + ((size_t)(b*NPIX + n))*8 + 4*h) = tv;
    }
#pragma unroll
    for (int r = 4; r < 16; ++r) {
        const int crow = (r&3) + 8*(r>>2) + 4*h;    // 8..31
        pool_s[crow - 8][pxb] = c0[r];
    }
#pragma unroll
    for (int r = 0; r < 8; ++r) {
        const int crow = (r&3) + 8*(r>>2) + 4*h;    // 0..15 -> gc 16..31
        pool_s[24 + crow][pxb] = c1[r];
    }
    __syncthreads();

    ushort* kvb = kv + (size_t)b * 40960;
    for (int i = t; i < 640; i += 256) {
        const int ch = i >> 4, mp = i & 15;
        const int cp = 4*mp;
        const float m0 = fmaxf(fmaxf(pool_s[ch][cp],   pool_s[ch][cp+1]),
                               fmaxf(pool_s[ch][64+cp], pool_s[ch][65+cp]));
        const float m1 = fmaxf(fmaxf(pool_s[ch][cp+2], pool_s[ch][cp+3]),
                               fmaxf(pool_s[ch][66+cp], pool_s[ch][67+cp]));
        const uint pk = cvtpk(m0, m1);
        const int key0 = rp*32 + 2*mp;
        if (ch < 8) {
            kvb[key0*8 + ch]     = (ushort)(pk & 0xFFFFu);
            kvb[(key0+1)*8 + ch] = (ushort)(pk >> 16);
        } else {
            const int gc = ch - 8;
            const int base = ((key0>>4)*64 + ((key0>>3)&1)*32 + gc)*8 + (key0&7);
            *(uint*)(kvb + 8192 + base) = pk;   // two keys, one dword
        }
    }
}

__global__ __launch_bounds__(512, 2) void attn_kernel(
    const float* __restrict__ x,  const ushort* __restrict__ thetaT,
    const ushort* __restrict__ kv, const float* __restrict__ Wo,
    const float* __restrict__ gammap, float* __restrict__ out)
{
    __shared__ __align__(16) char smem[81920];
    ushort* phiT_s  = (ushort*)smem;             // 16 KB [1024 key][8 c]
    ushort* gfrag_s = (ushort*)(smem + 16384);   // 64 KB [64 T][64 lane][8 j]

    const int t  = threadIdx.x;
    const int w  = t >> 6, l = t & 63, ql = l & 31, h = l >> 5;
    const int qg = w & 3, H = w >> 2;
    const int b  = blockIdx.x >> 4, qt = blockIdx.x & 15;
    const ushort* kvb = kv + (size_t)b * 40960;

    {
        const uint4* src = (const uint4*)kvb;
        uint4* dst = (uint4*)smem;
#pragma unroll
        for (int i = 0; i < 10; ++i) dst[t + i*512] = src[t + i*512];
    }

    const int nq0 = qt*256 + qg*64 + ql;
    U4B8 qv0, qv1;
    qv0.b = *(const bf16x8*)(thetaT + ((size_t)(b*NPIX + nq0))*8);
    qv1.b = *(const bf16x8*)(thetaT + ((size_t)(b*NPIX + nq0 + 32))*8);
    {
        const uint qm = h ? 0u : 0xFFFFFFFFu;
#pragma unroll
        for (int i = 0; i < 4; ++i) { qv0.u[i] &= qm; qv1.u[i] &= qm; }
    }
    __syncthreads();

    f32x16 acc0 = zero16(), acc1 = zero16();
    float lp0 = 0.0f, lp1 = 0.0f;

#pragma unroll 2
    for (int kt = 0; kt < 16; ++kt) {
        const bf16x8 af  = *(const bf16x8*)(phiT_s + ((H*512 + kt*32 + ql))*8);
        const bf16x8 gB0 = *(const bf16x8*)(gfrag_s + (((H*32 + kt*2 + 0)*64 + l))*8);
        const bf16x8 gB1 = *(const bf16x8*)(gfrag_s + (((H*32 + kt*2 + 1)*64 + l))*8);

        const f32x16 st0 = __builtin_amdgcn_mfma_f32_32x32x16_bf16(af, qv0.b, zero16(), 0,0,0);
        const f32x16 st1 = __builtin_amdgcn_mfma_f32_32x32x16_bf16(af, qv1.b, zero16(), 0,0,0);

#pragma unroll
        for (int f = 0; f < 2; ++f) {
            const f32x16& st = f ? st1 : st0;
            f32x16 P;
#pragma unroll
            for (int r = 0; r < 16; ++r) P[r] = __builtin_exp2f(st[r]);
            const float ls =
                  (((P[0]+P[1])+(P[2]+P[3])) + ((P[4]+P[5])+(P[6]+P[7])))
                + (((P[8]+P[9])+(P[10]+P[11])) + ((P[12]+P[13])+(P[14]+P[15])));
            if (f) lp1 += ls; else lp0 += ls;

#pragma unroll
            for (int ks = 0; ks < 2; ++ks) {
                const int bb = ks*8;
                uint X01 = cvtpk(P[bb+0], P[bb+1]);
                uint X23 = cvtpk(P[bb+2], P[bb+3]);
                uint Y01 = cvtpk(P[bb+4], P[bb+5]);
                uint Y23 = cvtpk(P[bb+6], P[bb+7]);
                asm("v_permlane32_swap_b32 %0, %1" : "+v"(X01), "+v"(Y01));
                asm("v_permlane32_swap_b32 %0, %1" : "+v"(X23), "+v"(Y23));
                U4B8 pa;
                pa.u[0] = X01; pa.u[1] = X23; pa.u[2] = Y01; pa.u[3] = Y23;
                if (f) acc1 = __builtin_amdgcn_mfma_f32_32x32x16_bf16(pa.b, ks ? gB1 : gB0, acc1, 0,0,0);
                else   acc0 = __builtin_amdgcn_mfma_f32_32x32x16_bf16(pa.b, ks ? gB1 : gB0, acc0, 0,0,0);
            }
        }
    }

    __syncthreads();                   // all K-loop LDS reads done
    float* avw = (float*)smem;         // [256 q][36]: 0-31 gc, 32 l
    if (H == 0) {
#pragma unroll
        for (int r = 0; r < 16; ++r) {
            const int crow = (r&3) + 8*(r>>2) + 4*h;
            avw[(qg*64 + crow)*36 + ql]      = acc0[r];
            avw[(qg*64 + 32 + crow)*36 + ql] = acc1[r];
        }
        float a0 = lp0, b0 = lp0, a1 = lp1, b1 = lp1;
        asm("v_permlane32_swap_b32 %0, %1" : "+v"(a0), "+v"(b0));
        asm("v_permlane32_swap_b32 %0, %1" : "+v"(a1), "+v"(b1));
        if (h == 0) {
            avw[(qg*64 + ql)*36 + 32]      = a0 + b0;
            avw[(qg*64 + 32 + ql)*36 + 32] = a1 + b1;
        }
    }
    __syncthreads();
    if (H == 1) {
#pragma unroll
        for (int r = 0; r < 16; ++r) {
            const int crow = (r&3) + 8*(r>>2) + 4*h;
            avw[(qg*64 + crow)*36 + ql]      += acc0[r];
            avw[(qg*64 + 32 + crow)*36 + ql] += acc1[r];
        }
        float a0 = lp0, b0 = lp0, a1 = lp1, b1 = lp1;
        asm("v_permlane32_swap_b32 %0, %1" : "+v"(a0), "+v"(b0));
        asm("v_permlane32_swap_b32 %0, %1" : "+v"(a1), "+v"(b1));
        if (h == 0) {
            avw[(qg*64 + ql)*36 + 32]      += a0 + b0;
            avw[(qg*64 + 32 + ql)*36 + 32] += a1 + b1;
        }
    }
    __syncthreads();

    const int qe  = (w & 3)*64 + (w >> 2)*32;   // this wave's 32-q group
    const int nqe = qt*256 + qe + ql;
    const float rinv = 1.0f / avw[(qe + ql)*36 + 32];
    bf16x8 avB[2];
#pragma unroll
    for (int s = 0; s < 2; ++s) {
        const float4 v0 = *(const float4*)&avw[(qe + ql)*36 + s*16 + h*8];
        const float4 v1 = *(const float4*)&avw[(qe + ql)*36 + s*16 + h*8 + 4];
        U4B8 cv;
        cv.u[0] = cvtpk(v0.x*rinv, v0.y*rinv); cv.u[1] = cvtpk(v0.z*rinv, v0.w*rinv);
        cv.u[2] = cvtpk(v1.x*rinv, v1.y*rinv); cv.u[3] = cvtpk(v1.z*rinv, v1.w*rinv);
        avB[s] = cv.b;
    }
    const float gamma = gammap[0];
    const float* xb = x   + (size_t)b*64*NPIX + nqe;
    float*       ob = out + (size_t)b*64*NPIX + nqe;
#pragma unroll
    for (int T = 0; T < 2; ++T) {
        f32x16 oacc = zero16();
#pragma unroll
        for (int s = 0; s < 2; ++s) {
            const float* wrow = Wo + (T*32 + ql)*32 + s*16 + h*8;
            U4B8 cv;
            cv.u[0] = cvtpk(wrow[0],wrow[1]); cv.u[1] = cvtpk(wrow[2],wrow[3]);
            cv.u[2] = cvtpk(wrow[4],wrow[5]); cv.u[3] = cvtpk(wrow[6],wrow[7]);
            oacc = __builtin_amdgcn_mfma_f32_32x32x16_bf16(cv.b, avB[s], oacc, 0,0,0);
        }
#pragma unroll
        for (int r = 0; r < 16; ++r) {
            const int oc = T*32 + (r&3) + 8*(r>>2) + 4*h;
            ob[(size_t)oc*NPIX] = gamma * oacc[r] + xb[(size_t)oc*NPIX];
        }
    }
}

extern "C" void kernel_launch(void* const* d_in, const int* in_sizes, int n_in,
                              void* d_out, int out_size, void* d_ws, size_t ws_size,
                              hipStream_t stream) {
    const float* x     = (const float*)d_in[0];
    const float* Wth   = (const float*)d_in[1];
    const float* Wph   = (const float*)d_in[2];
    const float* Wg    = (const float*)d_in[3];
    const float* Wo    = (const float*)d_in[4];
    const float* gamma = (const float*)d_in[5];
    float* out = (float*)d_out;

    ushort* thetaT = (ushort*)d_ws;                // 16*4096*8 ushort = 1 MB
    ushort* kv     = thetaT + (size_t)NB*NPIX*8;   // 16 * 40960 ushort

    proj_kernel<<<NB*32, 256, 0, stream>>>(x, Wth, Wph, Wg, thetaT, kv);
    // attn launched TWICE (idempotent): dur_us delta vs R7 = attn's true cost.
    attn_kernel<<<NB*16, 512, 0, stream>>>(x, thetaT, kv, Wo, gamma, out);
    attn_kernel<<<NB*16, 512, 0, stream>>>(x, thetaT, kv, Wo, gamma, out);
}

// Round 9
// 113.926 us; speedup vs baseline: 1.1701x; 1.1701x over previous
//
#include <hip/hip_runtime.h>

typedef unsigned int uint;
typedef unsigned short ushort;
typedef __attribute__((ext_vector_type(8))) short bf16x8;
typedef __attribute__((ext_vector_type(16))) float f32x16;

#define LOG2E 1.44269504088896f
#define NB 16
#define NPIX 4096   // 64*64 pixels per image
#define MKEY 1024   // pooled keys per image

// MEASUREMENT ROUND 2: bodies identical to R7/R8. proj_kernel launched TWICE
// (idempotent), attn once: dur_us(R9) - dur_us(R7) = proj's true marginal
// cost. Completes the budget decomposition {overhead, proj, attn}.

// ---- helpers -------------------------------------------------------------
__device__ inline uint cvtpk(float lo, float hi) {   // pack 2 f32 -> bf16x2 (RNE)
    uint r;
    asm("v_cvt_pk_bf16_f32 %0, %1, %2" : "=v"(r) : "v"(lo), "v"(hi));
    return r;
}
union U4B8 { uint u[4]; bf16x8 b; };
__device__ inline f32x16 zero16() {
    f32x16 z;
#pragma unroll
    for (int i = 0; i < 16; ++i) z[i] = 0.0f;
    return z;
}

// ws layout: thetaT bf16 [16][4096][8]  (524288 ushort)
//            per-b kv    [16] x { phiT bf16 [1024][8] (8192 us) |
//                                 g_frag bf16 [64 T][64 lane][8 j] (32768 us) }

__global__ __launch_bounds__(256, 2) void proj_kernel(
    const float* __restrict__ x,   const float* __restrict__ Wth,
    const float* __restrict__ Wph, const float* __restrict__ Wg,
    ushort* __restrict__ thetaT,   ushort* __restrict__ kv)
{
    __shared__ float wTs[64][66];       // [oc][c]
    __shared__ float pool_s[40][128];   // phi(0-7)/g(8-39) per-pixel values

    const int t  = threadIdx.x;
    const int w  = t >> 6, l = t & 63, ql = l & 31, h = l >> 5;
    const int b  = blockIdx.x >> 5, rp = blockIdx.x & 31;
    const int pxb = w*32 + ql;          // 0..127 within 2 image rows
    const int n   = rp*128 + pxb;       // global pixel

    for (int i = t; i < 4096; i += 256) {
        const int o = i >> 6, c = i & 63;
        float v;
        if (o < 8)       v = Wth[i] * LOG2E;
        else if (o < 16) v = Wph[i - 512];
        else if (o < 48) v = Wg[i - 1024];
        else             v = 0.0f;
        wTs[o][c] = v;
    }

    const float* xb = x + (size_t)b*64*NPIX + n;
    float xv[32];
#pragma unroll
    for (int k = 0; k < 32; ++k) {
        const int s = k >> 3, j = k & 7;
        xv[k] = xb[(size_t)(s*16 + h*8 + j) * NPIX];
    }
    __syncthreads();

    bf16x8 wA[2][4];
#pragma unroll
    for (int T = 0; T < 2; ++T)
#pragma unroll
        for (int s = 0; s < 4; ++s) {
            const float* p = &wTs[T*32 + ql][s*16 + h*8];
            U4B8 cv;
            cv.u[0] = cvtpk(p[0],p[1]); cv.u[1] = cvtpk(p[2],p[3]);
            cv.u[2] = cvtpk(p[4],p[5]); cv.u[3] = cvtpk(p[6],p[7]);
            wA[T][s] = cv.b;
        }

    f32x16 c0 = zero16(), c1 = zero16();
#pragma unroll
    for (int s = 0; s < 4; ++s) {
        U4B8 cv;
        cv.u[0] = cvtpk(xv[s*8+0],xv[s*8+1]); cv.u[1] = cvtpk(xv[s*8+2],xv[s*8+3]);
        cv.u[2] = cvtpk(xv[s*8+4],xv[s*8+5]); cv.u[3] = cvtpk(xv[s*8+6],xv[s*8+7]);
        c0 = __builtin_amdgcn_mfma_f32_32x32x16_bf16(wA[0][s], cv.b, c0, 0,0,0);
        c1 = __builtin_amdgcn_mfma_f32_32x32x16_bf16(wA[1][s], cv.b, c1, 0,0,0);
    }

    {
        uint2 tv;
        tv.x = cvtpk(c0[0], c0[1]);
        tv.y = cvtpk(c0[2], c0[3]);
        *(uint2*)(thetaT + ((size_t)(b*NPIX + n))*8 + 4*h) = tv;
    }
#pragma unroll
    for (int r = 4; r < 16; ++r) {
        const int crow = (r&3) + 8*(r>>2) + 4*h;    // 8..31
        pool_s[crow - 8][pxb] = c0[r];
    }
#pragma unroll
    for (int r = 0; r < 8; ++r) {
        const int crow = (r&3) + 8*(r>>2) + 4*h;    // 0..15 -> gc 16..31
        pool_s[24 + crow][pxb] = c1[r];
    }
    __syncthreads();

    ushort* kvb = kv + (size_t)b * 40960;
    for (int i = t; i < 640; i += 256) {
        const int ch = i >> 4, mp = i & 15;
        const int cp = 4*mp;
        const float m0 = fmaxf(fmaxf(pool_s[ch][cp],   pool_s[ch][cp+1]),
                               fmaxf(pool_s[ch][64+cp], pool_s[ch][65+cp]));
        const float m1 = fmaxf(fmaxf(pool_s[ch][cp+2], pool_s[ch][cp+3]),
                               fmaxf(pool_s[ch][66+cp], pool_s[ch][67+cp]));
        const uint pk = cvtpk(m0, m1);
        const int key0 = rp*32 + 2*mp;
        if (ch < 8) {
            kvb[key0*8 + ch]     = (ushort)(pk & 0xFFFFu);
            kvb[(key0+1)*8 + ch] = (ushort)(pk >> 16);
        } else {
            const int gc = ch - 8;
            const int base = ((key0>>4)*64 + ((key0>>3)&1)*32 + gc)*8 + (key0&7);
            *(uint*)(kvb + 8192 + base) = pk;   // two keys, one dword
        }
    }
}

__global__ __launch_bounds__(512, 2) void attn_kernel(
    const float* __restrict__ x,  const ushort* __restrict__ thetaT,
    const ushort* __restrict__ kv, const float* __restrict__ Wo,
    const float* __restrict__ gammap, float* __restrict__ out)
{
    __shared__ __align__(16) char smem[81920];
    ushort* phiT_s  = (ushort*)smem;             // 16 KB [1024 key][8 c]
    ushort* gfrag_s = (ushort*)(smem + 16384);   // 64 KB [64 T][64 lane][8 j]

    const int t  = threadIdx.x;
    const int w  = t >> 6, l = t & 63, ql = l & 31, h = l >> 5;
    const int qg = w & 3, H = w >> 2;
    const int b  = blockIdx.x >> 4, qt = blockIdx.x & 15;
    const ushort* kvb = kv + (size_t)b * 40960;

    {
        const uint4* src = (const uint4*)kvb;
        uint4* dst = (uint4*)smem;
#pragma unroll
        for (int i = 0; i < 10; ++i) dst[t + i*512] = src[t + i*512];
    }

    const int nq0 = qt*256 + qg*64 + ql;
    U4B8 qv0, qv1;
    qv0.b = *(const bf16x8*)(thetaT + ((size_t)(b*NPIX + nq0))*8);
    qv1.b = *(const bf16x8*)(thetaT + ((size_t)(b*NPIX + nq0 + 32))*8);
    {
        const uint qm = h ? 0u : 0xFFFFFFFFu;
#pragma unroll
        for (int i = 0; i < 4; ++i) { qv0.u[i] &= qm; qv1.u[i] &= qm; }
    }
    __syncthreads();

    f32x16 acc0 = zero16(), acc1 = zero16();
    float lp0 = 0.0f, lp1 = 0.0f;

#pragma unroll 2
    for (int kt = 0; kt < 16; ++kt) {
        const bf16x8 af  = *(const bf16x8*)(phiT_s + ((H*512 + kt*32 + ql))*8);
        const bf16x8 gB0 = *(const bf16x8*)(gfrag_s + (((H*32 + kt*2 + 0)*64 + l))*8);
        const bf16x8 gB1 = *(const bf16x8*)(gfrag_s + (((H*32 + kt*2 + 1)*64 + l))*8);

        const f32x16 st0 = __builtin_amdgcn_mfma_f32_32x32x16_bf16(af, qv0.b, zero16(), 0,0,0);
        const f32x16 st1 = __builtin_amdgcn_mfma_f32_32x32x16_bf16(af, qv1.b, zero16(), 0,0,0);

#pragma unroll
        for (int f = 0; f < 2; ++f) {
            const f32x16& st = f ? st1 : st0;
            f32x16 P;
#pragma unroll
            for (int r = 0; r < 16; ++r) P[r] = __builtin_exp2f(st[r]);
            const float ls =
                  (((P[0]+P[1])+(P[2]+P[3])) + ((P[4]+P[5])+(P[6]+P[7])))
                + (((P[8]+P[9])+(P[10]+P[11])) + ((P[12]+P[13])+(P[14]+P[15])));
            if (f) lp1 += ls; else lp0 += ls;

#pragma unroll
            for (int ks = 0; ks < 2; ++ks) {
                const int bb = ks*8;
                uint X01 = cvtpk(P[bb+0], P[bb+1]);
                uint X23 = cvtpk(P[bb+2], P[bb+3]);
                uint Y01 = cvtpk(P[bb+4], P[bb+5]);
                uint Y23 = cvtpk(P[bb+6], P[bb+7]);
                asm("v_permlane32_swap_b32 %0, %1" : "+v"(X01), "+v"(Y01));
                asm("v_permlane32_swap_b32 %0, %1" : "+v"(X23), "+v"(Y23));
                U4B8 pa;
                pa.u[0] = X01; pa.u[1] = X23; pa.u[2] = Y01; pa.u[3] = Y23;
                if (f) acc1 = __builtin_amdgcn_mfma_f32_32x32x16_bf16(pa.b, ks ? gB1 : gB0, acc1, 0,0,0);
                else   acc0 = __builtin_amdgcn_mfma_f32_32x32x16_bf16(pa.b, ks ? gB1 : gB0, acc0, 0,0,0);
            }
        }
    }

    __syncthreads();                   // all K-loop LDS reads done
    float* avw = (float*)smem;         // [256 q][36]: 0-31 gc, 32 l
    if (H == 0) {
#pragma unroll
        for (int r = 0; r < 16; ++r) {
            const int crow = (r&3) + 8*(r>>2) + 4*h;
            avw[(qg*64 + crow)*36 + ql]      = acc0[r];
            avw[(qg*64 + 32 + crow)*36 + ql] = acc1[r];
        }
        float a0 = lp0, b0 = lp0, a1 = lp1, b1 = lp1;
        asm("v_permlane32_swap_b32 %0, %1" : "+v"(a0), "+v"(b0));
        asm("v_permlane32_swap_b32 %0, %1" : "+v"(a1), "+v"(b1));
        if (h == 0) {
            avw[(qg*64 + ql)*36 + 32]      = a0 + b0;
            avw[(qg*64 + 32 + ql)*36 + 32] = a1 + b1;
        }
    }
    __syncthreads();
    if (H == 1) {
#pragma unroll
        for (int r = 0; r < 16; ++r) {
            const int crow = (r&3) + 8*(r>>2) + 4*h;
            avw[(qg*64 + crow)*36 + ql]      += acc0[r];
            avw[(qg*64 + 32 + crow)*36 + ql] += acc1[r];
        }
        float a0 = lp0, b0 = lp0, a1 = lp1, b1 = lp1;
        asm("v_permlane32_swap_b32 %0, %1" : "+v"(a0), "+v"(b0));
        asm("v_permlane32_swap_b32 %0, %1" : "+v"(a1), "+v"(b1));
        if (h == 0) {
            avw[(qg*64 + ql)*36 + 32]      += a0 + b0;
            avw[(qg*64 + 32 + ql)*36 + 32] += a1 + b1;
        }
    }
    __syncthreads();

    const int qe  = (w & 3)*64 + (w >> 2)*32;   // this wave's 32-q group
    const int nqe = qt*256 + qe + ql;
    const float rinv = 1.0f / avw[(qe + ql)*36 + 32];
    bf16x8 avB[2];
#pragma unroll
    for (int s = 0; s < 2; ++s) {
        const float4 v0 = *(const float4*)&avw[(qe + ql)*36 + s*16 + h*8];
        const float4 v1 = *(const float4*)&avw[(qe + ql)*36 + s*16 + h*8 + 4];
        U4B8 cv;
        cv.u[0] = cvtpk(v0.x*rinv, v0.y*rinv); cv.u[1] = cvtpk(v0.z*rinv, v0.w*rinv);
        cv.u[2] = cvtpk(v1.x*rinv, v1.y*rinv); cv.u[3] = cvtpk(v1.z*rinv, v1.w*rinv);
        avB[s] = cv.b;
    }
    const float gamma = gammap[0];
    const float* xb = x   + (size_t)b*64*NPIX + nqe;
    float*       ob = out + (size_t)b*64*NPIX + nqe;
#pragma unroll
    for (int T = 0; T < 2; ++T) {
        f32x16 oacc = zero16();
#pragma unroll
        for (int s = 0; s < 2; ++s) {
            const float* wrow = Wo + (T*32 + ql)*32 + s*16 + h*8;
            U4B8 cv;
            cv.u[0] = cvtpk(wrow[0],wrow[1]); cv.u[1] = cvtpk(wrow[2],wrow[3]);
            cv.u[2] = cvtpk(wrow[4],wrow[5]); cv.u[3] = cvtpk(wrow[6],wrow[7]);
            oacc = __builtin_amdgcn_mfma_f32_32x32x16_bf16(cv.b, avB[s], oacc, 0,0,0);
        }
#pragma unroll
        for (int r = 0; r < 16; ++r) {
            const int oc = T*32 + (r&3) + 8*(r>>2) + 4*h;
            ob[(size_t)oc*NPIX] = gamma * oacc[r] + xb[(size_t)oc*NPIX];
        }
    }
}

extern "C" void kernel_launch(void* const* d_in, const int* in_sizes, int n_in,
                              void* d_out, int out_size, void* d_ws, size_t ws_size,
                              hipStream_t stream) {
    const float* x     = (const float*)d_in[0];
    const float* Wth   = (const float*)d_in[1];
    const float* Wph   = (const float*)d_in[2];
    const float* Wg    = (const float*)d_in[3];
    const float* Wo    = (const float*)d_in[4];
    const float* gamma = (const float*)d_in[5];
    float* out = (float*)d_out;

    ushort* thetaT = (ushort*)d_ws;                // 16*4096*8 ushort = 1 MB
    ushort* kv     = thetaT + (size_t)NB*NPIX*8;   // 16 * 40960 ushort

    // proj launched TWICE (idempotent): dur_us delta vs R7 = proj's true cost.
    proj_kernel<<<NB*32, 256, 0, stream>>>(x, Wth, Wph, Wg, thetaT, kv);
    proj_kernel<<<NB*32, 256, 0, stream>>>(x, Wth, Wph, Wg, thetaT, kv);
    attn_kernel<<<NB*16, 512, 0, stream>>>(x, thetaT, kv, Wo, gamma, out);
}

// Round 11
// 105.382 us; speedup vs baseline: 1.2649x; 1.0811x over previous
//
#include <hip/hip_runtime.h>

typedef unsigned int uint;
typedef unsigned short ushort;
typedef __attribute__((ext_vector_type(8))) short bf16x8;
typedef __attribute__((ext_vector_type(16))) float f32x16;

#define LOG2E 1.44269504088896f
#define NB 16
#define NPIX 4096   // 64*64 pixels per image
#define MKEY 1024   // pooled keys per image

// ---- helpers -------------------------------------------------------------
__device__ inline uint cvtpk(float lo, float hi) {   // pack 2 f32 -> bf16x2 (RNE)
    uint r;
    asm("v_cvt_pk_bf16_f32 %0, %1, %2" : "=v"(r) : "v"(lo), "v"(hi));
    return r;
}
union U4B8 { uint u[4]; bf16x8 b; };
__device__ inline f32x16 zero16() {
    f32x16 z;
#pragma unroll
    for (int i = 0; i < 16; ++i) z[i] = 0.0f;
    return z;
}

// ws layout: thetaT bf16 [16][4096][8]  (524288 ushort)
//            per-b kv    [16] x { phiT bf16 [1024][8] (8192 us) |
//                                 g_frag bf16 [64 T][64 lane][8 j] (32768 us) }

__global__ __launch_bounds__(256, 2) void proj_kernel(
    const float* __restrict__ x,   const float* __restrict__ Wth,
    const float* __restrict__ Wph, const float* __restrict__ Wg,
    ushort* __restrict__ thetaT,   ushort* __restrict__ kv)
{
    __shared__ float wTs[64][66];       // [oc][c]
    __shared__ float pool_s[40][128];   // phi(0-7)/g(8-39) per-pixel values

    const int t  = threadIdx.x;
    const int w  = t >> 6, l = t & 63, ql = l & 31, h = l >> 5;
    const int b  = blockIdx.x >> 5, rp = blockIdx.x & 31;
    const int pxb = w*32 + ql;          // 0..127 within 2 image rows
    const int n   = rp*128 + pxb;       // global pixel

    for (int i = t; i < 4096; i += 256) {
        const int o = i >> 6, c = i & 63;
        float v;
        if (o < 8)       v = Wth[i] * LOG2E;
        else if (o < 16) v = Wph[i - 512];
        else if (o < 48) v = Wg[i - 1024];
        else             v = 0.0f;
        wTs[o][c] = v;
    }

    const float* xb = x + (size_t)b*64*NPIX + n;
    float xv[32];
#pragma unroll
    for (int k = 0; k < 32; ++k) {
        const int s = k >> 3, j = k & 7;
        xv[k] = xb[(size_t)(s*16 + h*8 + j) * NPIX];
    }
    __syncthreads();

    bf16x8 wA[2][4];
#pragma unroll
    for (int T = 0; T < 2; ++T)
#pragma unroll
        for (int s = 0; s < 4; ++s) {
            const float* p = &wTs[T*32 + ql][s*16 + h*8];
            U4B8 cv;
            cv.u[0] = cvtpk(p[0],p[1]); cv.u[1] = cvtpk(p[2],p[3]);
            cv.u[2] = cvtpk(p[4],p[5]); cv.u[3] = cvtpk(p[6],p[7]);
            wA[T][s] = cv.b;
        }

    f32x16 c0 = zero16(), c1 = zero16();
#pragma unroll
    for (int s = 0; s < 4; ++s) {
        U4B8 cv;
        cv.u[0] = cvtpk(xv[s*8+0],xv[s*8+1]); cv.u[1] = cvtpk(xv[s*8+2],xv[s*8+3]);
        cv.u[2] = cvtpk(xv[s*8+4],xv[s*8+5]); cv.u[3] = cvtpk(xv[s*8+6],xv[s*8+7]);
        c0 = __builtin_amdgcn_mfma_f32_32x32x16_bf16(wA[0][s], cv.b, c0, 0,0,0);
        c1 = __builtin_amdgcn_mfma_f32_32x32x16_bf16(wA[1][s], cv.b, c1, 0,0,0);
    }

    {
        uint2 tv;
        tv.x = cvtpk(c0[0], c0[1]);
        tv.y = cvtpk(c0[2], c0[3]);
        *(uint2*)(thetaT + ((size_t)(b*NPIX + n))*8 + 4*h) = tv;
    }
#pragma unroll
    for (int r = 4; r < 16; ++r) {
        const int crow = (r&3) + 8*(r>>2) + 4*h;    // 8..31
        pool_s[crow - 8][pxb] = c0[r];
    }
#pragma unroll
    for (int r = 0; r < 8; ++r) {
        const int crow = (r&3) + 8*(r>>2) + 4*h;    // 0..15 -> gc 16..31
        pool_s[24 + crow][pxb] = c1[r];
    }
    __syncthreads();

    ushort* kvb = kv + (size_t)b * 40960;
    for (int i = t; i < 640; i += 256) {
        const int ch = i >> 4, mp = i & 15;
        const int cp = 4*mp;
        const float m0 = fmaxf(fmaxf(pool_s[ch][cp],   pool_s[ch][cp+1]),
                               fmaxf(pool_s[ch][64+cp], pool_s[ch][65+cp]));
        const float m1 = fmaxf(fmaxf(pool_s[ch][cp+2], pool_s[ch][cp+3]),
                               fmaxf(pool_s[ch][66+cp], pool_s[ch][67+cp]));
        const uint pk = cvtpk(m0, m1);
        const int key0 = rp*32 + 2*mp;
        if (ch < 8) {
            kvb[key0*8 + ch]     = (ushort)(pk & 0xFFFFu);
            kvb[(key0+1)*8 + ch] = (ushort)(pk >> 16);
        } else {
            const int gc = ch - 8;
            const int base = ((key0>>4)*64 + ((key0>>3)&1)*32 + gc)*8 + (key0&7);
            *(uint*)(kvb + 8192 + base) = pk;   // two keys, one dword
        }
    }
}

// -------------------------------------------------------------------------
// Kernel 2: flash attention + W_o + residual, all MFMA.
// TLP round: 512 blocks (16 b x 32 q-tiles of 128 q), 512 thr = 8 waves =
// 4 q-frags (32 q) x 2 key-halves. ONE q-fragment per wave (half the serial
// kt depth of R7) and 2x the wave count: 4096 waves = 4 waves/SIMD (was 2).
// LDS 80 KB staging -> 2 blocks/CU (160 KB exactly), 16 waves/CU.
// launch_bounds(512,4) caps VGPR at 128 so 4 waves/SIMD fit.
// Epilogue parallelized too: wave (qg,H) computes oc-tile T=H.
// -------------------------------------------------------------------------
__global__ __launch_bounds__(512, 4) void attn_kernel(
    const float* __restrict__ x,  const ushort* __restrict__ thetaT,
    const ushort* __restrict__ kv, const float* __restrict__ Wo,
    const float* __restrict__ gammap, float* __restrict__ out)
{
    __shared__ __align__(16) char smem[81920];
    ushort* phiT_s  = (ushort*)smem;             // 16 KB [1024 key][8 c]
    ushort* gfrag_s = (ushort*)(smem + 16384);   // 64 KB [64 T][64 lane][8 j]

    const int t  = threadIdx.x;
    const int w  = t >> 6, l = t & 63, ql = l & 31, h = l >> 5;
    const int qg = w & 3, H = w >> 2;
    const int b  = blockIdx.x >> 5, qt = blockIdx.x & 31;
    const ushort* kvb = kv + (size_t)b * 40960;

    // stage all 1024 keys: 80 KB = 5120 uint4, 10 per thread
    {
        const uint4* src = (const uint4*)kvb;
        uint4* dst = (uint4*)smem;
#pragma unroll
        for (int i = 0; i < 10; ++i) dst[t + i*512] = src[t + i*512];
    }

    // Q fragment (B-operand): k 0-7 real theta, k 8-15 zero
    const int nq0 = qt*128 + qg*32 + ql;
    U4B8 qv;
    qv.b = *(const bf16x8*)(thetaT + ((size_t)(b*NPIX + nq0))*8);
    {
        const uint qm = h ? 0u : 0xFFFFFFFFu;
#pragma unroll
        for (int i = 0; i < 4; ++i) qv.u[i] &= qm;
    }
    __syncthreads();

    f32x16 acc = zero16();
    float lp = 0.0f;

#pragma unroll 2
    for (int kt = 0; kt < 16; ++kt) {
        const bf16x8 af  = *(const bf16x8*)(phiT_s + ((H*512 + kt*32 + ql))*8);
        const bf16x8 gB0 = *(const bf16x8*)(gfrag_s + (((H*32 + kt*2 + 0)*64 + l))*8);
        const bf16x8 gB1 = *(const bf16x8*)(gfrag_s + (((H*32 + kt*2 + 1)*64 + l))*8);

        const f32x16 st = __builtin_amdgcn_mfma_f32_32x32x16_bf16(af, qv.b, zero16(), 0,0,0);
        f32x16 P;
#pragma unroll
        for (int r = 0; r < 16; ++r) P[r] = __builtin_exp2f(st[r]);
        lp += (((P[0]+P[1])+(P[2]+P[3])) + ((P[4]+P[5])+(P[6]+P[7])))
            + (((P[8]+P[9])+(P[10]+P[11])) + ((P[12]+P[13])+(P[14]+P[15])));

#pragma unroll
        for (int ks = 0; ks < 2; ++ks) {
            const int bb = ks*8;
            uint X01 = cvtpk(P[bb+0], P[bb+1]);
            uint X23 = cvtpk(P[bb+2], P[bb+3]);
            uint Y01 = cvtpk(P[bb+4], P[bb+5]);
            uint Y23 = cvtpk(P[bb+6], P[bb+7]);
            // X' = [Xlo|Ylo], Y' = [Xhi|Yhi] -> both PV A-frag words
            asm("v_permlane32_swap_b32 %0, %1" : "+v"(X01), "+v"(Y01));
            asm("v_permlane32_swap_b32 %0, %1" : "+v"(X23), "+v"(Y23));
            U4B8 pa;
            pa.u[0] = X01; pa.u[1] = X23; pa.u[2] = Y01; pa.u[3] = Y23;
            acc = __builtin_amdgcn_mfma_f32_32x32x16_bf16(pa.b, ks ? gB1 : gB0, acc, 0,0,0);
        }
    }

    // -------- combine the two key-halves through LDS --------
    __syncthreads();                   // all K-loop LDS reads done
    float* avw = (float*)smem;         // [128 q][36]: 0-31 gc, 32 l
    if (H == 0) {
#pragma unroll
        for (int r = 0; r < 16; ++r) {
            const int crow = (r&3) + 8*(r>>2) + 4*h;
            avw[(qg*32 + crow)*36 + ql] = acc[r];
        }
        float a0 = lp, b0 = lp;
        asm("v_permlane32_swap_b32 %0, %1" : "+v"(a0), "+v"(b0));
        if (h == 0) avw[(qg*32 + ql)*36 + 32] = a0 + b0;
    }
    __syncthreads();
    if (H == 1) {
#pragma unroll
        for (int r = 0; r < 16; ++r) {
            const int crow = (r&3) + 8*(r>>2) + 4*h;
            avw[(qg*32 + crow)*36 + ql] += acc[r];
        }
        float a0 = lp, b0 = lp;
        asm("v_permlane32_swap_b32 %0, %1" : "+v"(a0), "+v"(b0));
        if (h == 0) avw[(qg*32 + ql)*36 + 32] += a0 + b0;
    }
    __syncthreads();

    // -------- epilogue: wave (qg,H) computes oc-tile T=H for its 32 q ----
    const int nqe = qt*128 + qg*32 + ql;
    const float rinv = 1.0f / avw[(qg*32 + ql)*36 + 32];
    bf16x8 avB[2];
#pragma unroll
    for (int s = 0; s < 2; ++s) {
        const float4 v0 = *(const float4*)&avw[(qg*32 + ql)*36 + s*16 + h*8];
        const float4 v1 = *(const float4*)&avw[(qg*32 + ql)*36 + s*16 + h*8 + 4];
        U4B8 cv;
        cv.u[0] = cvtpk(v0.x*rinv, v0.y*rinv); cv.u[1] = cvtpk(v0.z*rinv, v0.w*rinv);
        cv.u[2] = cvtpk(v1.x*rinv, v1.y*rinv); cv.u[3] = cvtpk(v1.z*rinv, v1.w*rinv);
        avB[s] = cv.b;
    }
    const float gamma = gammap[0];
    const float* xb = x   + (size_t)b*64*NPIX + nqe;
    float*       ob = out + (size_t)b*64*NPIX + nqe;
    {
        f32x16 oacc = zero16();
#pragma unroll
        for (int s = 0; s < 2; ++s) {
            const float* wrow = Wo + (H*32 + ql)*32 + s*16 + h*8;
            U4B8 cv;
            cv.u[0] = cvtpk(wrow[0],wrow[1]); cv.u[1] = cvtpk(wrow[2],wrow[3]);
            cv.u[2] = cvtpk(wrow[4],wrow[5]); cv.u[3] = cvtpk(wrow[6],wrow[7]);
            oacc = __builtin_amdgcn_mfma_f32_32x32x16_bf16(cv.b, avB[s], oacc, 0,0,0);
        }
#pragma unroll
        for (int r = 0; r < 16; ++r) {
            const int oc = H*32 + (r&3) + 8*(r>>2) + 4*h;
            ob[(size_t)oc*NPIX] = gamma * oacc[r] + xb[(size_t)oc*NPIX];
        }
    }
}

extern "C" void kernel_launch(void* const* d_in, const int* in_sizes, int n_in,
                              void* d_out, int out_size, void* d_ws, size_t ws_size,
                              hipStream_t stream) {
    const float* x     = (const float*)d_in[0];
    const float* Wth   = (const float*)d_in[1];
    const float* Wph   = (const float*)d_in[2];
    const float* Wg    = (const float*)d_in[3];
    const float* Wo    = (const float*)d_in[4];
    const float* gamma = (const float*)d_in[5];
    float* out = (float*)d_out;

    ushort* thetaT = (ushort*)d_ws;                // 16*4096*8 ushort = 1 MB
    ushort* kv     = thetaT + (size_t)NB*NPIX*8;   // 16 * 40960 ushort

    proj_kernel<<<NB*32, 256, 0, stream>>>(x, Wth, Wph, Wg, thetaT, kv);
    attn_kernel<<<NB*32, 512, 0, stream>>>(x, thetaT, kv, Wo, gamma, out);
}